// Round 7
// baseline (303.535 us; speedup 1.0000x reference)
//
#include <hip/hip_runtime.h>
#include <hip/hip_bf16.h>
#include <stdint.h>

#define NODES 50000
#define EDGES 800000
#define R_REP 8
#define SCAN_TB 256
#define SCAN_NB ((NODES + SCAN_TB - 1) / SCAN_TB)   // 196

typedef short bf16x8 __attribute__((ext_vector_type(8)));
typedef float f32x4 __attribute__((ext_vector_type(4)));

__device__ __forceinline__ unsigned short f2bf(float f) {
    union { float f; unsigned u; } v; v.f = f;
    unsigned r = v.u + 0x7fff + ((v.u >> 16) & 1);   // RNE
    return (unsigned short)(r >> 16);
}
__device__ __forceinline__ float bf2f(unsigned short h) {
    union { float f; unsigned u; } v; v.u = ((unsigned)h) << 16;
    return v.f;
}
__device__ __forceinline__ float bflo(unsigned hv) {
    union { float f; unsigned u; } v; v.u = hv << 16;
    return v.f;
}
__device__ __forceinline__ float bfhi(unsigned hv) {
    union { float f; unsigned u; } v; v.u = hv & 0xffff0000u;
    return v.f;
}

// ---------------- setup: zero replicated counters + W pre-swizzle ----------------
// packed[i*R_REP+r] (node-major interleave: all 8 replicas of a node share one
// 64B line -> 16 RMWs/line, and scan1 reads a node's replicas contiguously).
// bits[63:40]=count, bits[39:0]=weighted degree (2^24 fx). Self-loop added at scan.

__device__ __forceinline__ void wfrag_one(const float* __restrict__ W, unsigned short* Wf,
                                          int idx, int K, int Nn) {
    int NT = Nn >> 4;
    int lane = idx & 63;
    int f = idx >> 6;
    int nt = f % NT;
    int k0 = (f / NT) << 5;
    int n = (nt << 4) + (lane & 15);
    int kk = k0 + ((lane >> 4) << 3);
    unsigned short o[8];
#pragma unroll
    for (int j = 0; j < 8; j++) o[j] = f2bf(W[(kk + j) * Nn + n]);
    ((uint4*)Wf)[idx] = *(uint4*)o;
}

__global__ void k_setup(unsigned long long* packed,
                        const float* __restrict__ W1, unsigned short* Wf1,
                        const float* __restrict__ W2, unsigned short* Wf2,
                        const float* __restrict__ W3, unsigned short* Wf3) {
    int idx = blockIdx.x * blockDim.x + threadIdx.x;
    if (idx < NODES * R_REP) { packed[idx] = 0ull; return; }
    int k = idx - NODES * R_REP;
    if (k < 4096) wfrag_one(W1, Wf1, k, 256, 128);
    else if (k < 6144) wfrag_one(W2, Wf2, k - 4096, 128, 128);
    else if (k < 7168) wfrag_one(W3, Wf3, k - 6144, 128, 64);
}

__global__ void k_deg(const int* __restrict__ dst, const float* __restrict__ w,
                      unsigned long long* __restrict__ packed, int* __restrict__ rank) {
    int e = blockIdx.x * blockDim.x + threadIdx.x;
    int r = blockIdx.x & (R_REP - 1);
    if (e < EDGES) {
        int d = dst[e];
        unsigned fx = __float2uint_rn(w[e] * 16777216.0f);   // w * 2^24
        unsigned long long add = (1ull << 40) | (unsigned long long)fx;
        unsigned long long old = atomicAdd(&packed[(size_t)d * R_REP + r], add);
        rank[e] = (int)(old >> 40);
    }
}

// ---- scan1: reduce replicas -> dis + per-replica offsets; block-scan counts ----

__global__ void k_scan1(const unsigned long long* __restrict__ packed,
                        float* __restrict__ dis, int* __restrict__ repoff,
                        int* __restrict__ pre, int* __restrict__ bsum) {
    __shared__ int sm[SCAN_TB];
    int t = threadIdx.x;
    int i = blockIdx.x * SCAN_TB + t;
    int v = 0;
    if (i < NODES) {
        unsigned long long degfx = 0;
        int off = 0;
#pragma unroll
        for (int r = 0; r < R_REP; r++) {
            unsigned long long pk = packed[(size_t)i * R_REP + r];
            repoff[(size_t)r * NODES + i] = off;   // exclusive prefix over replicas
            off += (int)(pk >> 40);
            degfx += (pk & 0xFFFFFFFFFFull);
        }
        v = off;
        float deg = 1.0f + (float)degfx * (1.0f / 16777216.0f);   // +1: self-loop
        dis[i] = rsqrtf(deg);
    }
    sm[t] = v;
    __syncthreads();
    for (int off = 1; off < SCAN_TB; off <<= 1) {
        int x = (t >= off) ? sm[t - off] : 0;
        __syncthreads();
        sm[t] += x;
        __syncthreads();
    }
    if (i < NODES) pre[i] = sm[t] - v;              // exclusive within block
    if (t == SCAN_TB - 1) bsum[blockIdx.x] = sm[t]; // block total
}

__global__ void k_scan2(const int* __restrict__ bsum, int* __restrict__ boff,
                        int* __restrict__ rowptr) {
    __shared__ int sm[256];
    int t = threadIdx.x;
    int v = (t < SCAN_NB) ? bsum[t] : 0;
    sm[t] = v;
    __syncthreads();
    for (int off = 1; off < 256; off <<= 1) {
        int x = (t >= off) ? sm[t - off] : 0;
        __syncthreads();
        sm[t] += x;
        __syncthreads();
    }
    if (t < SCAN_NB) boff[t] = sm[t] - v;
    if (t == 255) rowptr[NODES] = sm[255];          // total = EDGES
}

// atomic-free scatter: pos = (pre[d]+boff[d/256]) + replica offset + rank.
// Also writes rowptr[i]. Grid shape MUST match k_deg so r matches per edge.
__global__ void k_scatter(const int* __restrict__ src, const int* __restrict__ dst,
                          const float* __restrict__ w, const float* __restrict__ dis,
                          const int* __restrict__ pre, const int* __restrict__ boff,
                          const int* __restrict__ repoff, const int* __restrict__ rank,
                          int2* __restrict__ rec, int* __restrict__ rowptr) {
    int e = blockIdx.x * blockDim.x + threadIdx.x;
    int r = blockIdx.x & (R_REP - 1);
    if (e < NODES) rowptr[e] = pre[e] + boff[e >> 8];
    if (e < EDGES) {
        int s = src[e], d = dst[e];
        float nrm = dis[s] * w[e] * dis[d];
        int pos = pre[d] + boff[d >> 8] + repoff[(size_t)r * NODES + d] + rank[e];
        int2 rc; rc.x = s; rc.y = __float_as_int(nrm);
        rec[pos] = rc;
    }
}

// ---------------- GEMM: H[M,N] = A[M,K] @ W[K,N] (bf16 MFMA, fp32 acc) ----------------
template <int K, int Nn, bool A_F32>
__global__ void k_gemm(const void* __restrict__ A_, const uint4* __restrict__ Wf,
                       unsigned short* __restrict__ Hout) {
    constexpr int NT = Nn / 16;
    int lane = threadIdx.x & 63;
    int wave = threadIdx.x >> 6;
    int tile = blockIdx.x * 4 + wave;
    if (tile * 16 >= NODES) return;
    int row = tile * 16 + (lane & 15);
    int kbase = (lane >> 4) * 8;

    f32x4 acc[NT];
#pragma unroll
    for (int i = 0; i < NT; i++) acc[i] = (f32x4){0.f, 0.f, 0.f, 0.f};

    for (int k0 = 0; k0 < K; k0 += 32) {
        bf16x8 a;
        if (A_F32) {
            const float* A = (const float*)A_;
            const float4* p = (const float4*)&A[(size_t)row * K + k0 + kbase];
            float4 u0 = p[0], u1 = p[1];
            unsigned short t[8];
            t[0] = f2bf(u0.x); t[1] = f2bf(u0.y); t[2] = f2bf(u0.z); t[3] = f2bf(u0.w);
            t[4] = f2bf(u1.x); t[5] = f2bf(u1.y); t[6] = f2bf(u1.z); t[7] = f2bf(u1.w);
            a = *(bf16x8*)t;
        } else {
            const unsigned short* A = (const unsigned short*)A_;
            a = *(const bf16x8*)&A[(size_t)row * K + k0 + kbase];
        }
        int fbase = (k0 >> 5) * NT;
#pragma unroll
        for (int nt = 0; nt < NT; nt++) {
            uint4 braw = Wf[(fbase + nt) * 64 + lane];
            bf16x8 b = *(bf16x8*)&braw;
            acc[nt] = __builtin_amdgcn_mfma_f32_16x16x32_bf16(a, b, acc[nt], 0, 0, 0);
        }
    }
    int r0 = (lane >> 4) * 4;
    int col = lane & 15;
#pragma unroll
    for (int nt = 0; nt < NT; nt++) {
#pragma unroll
        for (int r = 0; r < 4; r++) {
            int m = tile * 16 + r0 + r;
            Hout[(size_t)m * Nn + nt * 16 + col] = f2bf(acc[nt][r]);
        }
    }
}

// ---------------- Aggregation ----------------
// One wave per node, records on the scalar path (wave-uniform, readfirstlane-
// pinned -> SGPRs). 16 gathers in flight; next chunk's 16 records prefetched
// while current chunk's gathers are outstanding. Tail: uniform clamp + zero
// norm so the pipeline stays 16 deep with no divergence.
template <int F, bool RELU, bool OUT_F32>
__global__ void k_agg(const unsigned short* __restrict__ H, const int2* __restrict__ rec,
                      const int* __restrict__ rowptr, const float* __restrict__ dis,
                      const float* __restrict__ bias, void* __restrict__ out_) {
    constexpr int VPT = F / 64;
    int lane = threadIdx.x & 63;
    int node = blockIdx.x * 4 + (threadIdx.x >> 6);
    if (node >= NODES) return;
    node = __builtin_amdgcn_readfirstlane(node);   // wave-uniform -> SGPR

    const unsigned* H32 = (const unsigned*)H;

    float sn = dis[node]; sn = sn * sn;   // dis^2 = 1/deg (self-loop norm)
    float acc0, acc1 = 0.f;
    if (VPT == 2) {
        unsigned hv = H32[node * 64 + lane];
        acc0 = sn * bflo(hv);
        acc1 = sn * bfhi(hv);
    } else {
        acc0 = sn * bf2f(H[node * 64 + lane]);
    }

    int beg = rowptr[node], end = rowptr[node + 1];
    int last = end - 1;

    int cs[16]; float cn[16];
#pragma unroll
    for (int q = 0; q < 16; q++) {
        int idx = beg + q; idx = (idx < last) ? idx : last;   // uniform clamp
        int2 rc = rec[idx];
        cs[q] = __builtin_amdgcn_readfirstlane(rc.x);
        cn[q] = (beg + q < end) ? __int_as_float(rc.y) : 0.0f;
    }

    for (int j = beg; j < end; j += 16) {
        // prefetch next chunk's records (scalar loads overlap current gathers)
        int ns[16]; float nn[16];
        int jn = j + 16;
        if (jn < end) {
#pragma unroll
            for (int q = 0; q < 16; q++) {
                int idx = jn + q; idx = (idx < last) ? idx : last;
                int2 rc = rec[idx];
                ns[q] = __builtin_amdgcn_readfirstlane(rc.x);
                nn[q] = (jn + q < end) ? __int_as_float(rc.y) : 0.0f;
            }
        }
        if (VPT == 2) {
            unsigned hh[16];
#pragma unroll
            for (int q = 0; q < 16; q++) hh[q] = H32[cs[q] * 64 + lane];
#pragma unroll
            for (int q = 0; q < 16; q++) {
                acc0 += cn[q] * bflo(hh[q]);
                acc1 += cn[q] * bfhi(hh[q]);
            }
        } else {
            unsigned short hh[16];
#pragma unroll
            for (int q = 0; q < 16; q++) hh[q] = H[cs[q] * 64 + lane];
#pragma unroll
            for (int q = 0; q < 16; q++) acc0 += cn[q] * bf2f(hh[q]);
        }
        if (jn < end) {
#pragma unroll
            for (int q = 0; q < 16; q++) { cs[q] = ns[q]; cn[q] = nn[q]; }
        }
    }

    if (OUT_F32) {
        float* out = (float*)out_;
        if (VPT == 2) {
            float x0 = acc0 + bias[lane * 2];
            float x1 = acc1 + bias[lane * 2 + 1];
            if (RELU) { x0 = fmaxf(x0, 0.f); x1 = fmaxf(x1, 0.f); }
            out[(size_t)node * F + lane * 2] = x0;
            out[(size_t)node * F + lane * 2 + 1] = x1;
        } else {
            float x0 = acc0 + bias[lane];
            if (RELU) x0 = fmaxf(x0, 0.f);
            out[(size_t)node * F + lane] = x0;
        }
    } else {
        unsigned short* out = (unsigned short*)out_;
        if (VPT == 2) {
            float x0 = acc0 + bias[lane * 2];
            float x1 = acc1 + bias[lane * 2 + 1];
            if (RELU) { x0 = fmaxf(x0, 0.f); x1 = fmaxf(x1, 0.f); }
            unsigned packed = (unsigned)f2bf(x0) | ((unsigned)f2bf(x1) << 16);
            *(unsigned*)&out[(size_t)node * F + lane * 2] = packed;
        } else {
            float x0 = acc0 + bias[lane];
            if (RELU) x0 = fmaxf(x0, 0.f);
            out[(size_t)node * F + lane] = f2bf(x0);
        }
    }
}

// ---------------- launch ----------------

extern "C" void kernel_launch(void* const* d_in, const int* in_sizes, int n_in,
                              void* d_out, int out_size, void* d_ws, size_t ws_size,
                              hipStream_t stream) {
    const float* x  = (const float*)d_in[0];
    const int*   ei = (const int*)d_in[1];
    const float* w  = (const float*)d_in[2];
    const float* W1 = (const float*)d_in[3];
    const float* b1 = (const float*)d_in[4];
    const float* W2 = (const float*)d_in[5];
    const float* b2 = (const float*)d_in[6];
    const float* W3 = (const float*)d_in[7];
    const float* b3 = (const float*)d_in[8];
    const int* src = ei;
    const int* dst = ei + EDGES;

    char* p = (char*)d_ws;
    auto alloc = [&](size_t n) { char* r = p; p += (n + 511) & ~(size_t)511; return r; };
    unsigned long long* packed = (unsigned long long*)alloc((size_t)NODES * R_REP * 8);
    float*          dis    = (float*)alloc(NODES * 4);
    int*            rowptr = (int*)alloc((NODES + 1) * 4);
    int*            repoff = (int*)alloc((size_t)NODES * R_REP * 4);
    int*            rank   = (int*)alloc(EDGES * 4);
    int*            pre    = (int*)alloc(NODES * 4);
    int*            bsum   = (int*)alloc(SCAN_NB * 4);
    int*            boff   = (int*)alloc(SCAN_NB * 4);
    int2*           rec    = (int2*)alloc(EDGES * 8);
    unsigned short* h      = (unsigned short*)alloc((size_t)NODES * 128 * 2);
    unsigned short* xb     = (unsigned short*)alloc((size_t)NODES * 128 * 2);
    unsigned short* wf1    = (unsigned short*)alloc(256 * 128 * 2);
    unsigned short* wf2    = (unsigned short*)alloc(128 * 128 * 2);
    unsigned short* wf3    = (unsigned short*)alloc(128 * 64 * 2);

    const int TB = 256;
    int nb_setup = (NODES * R_REP + 7168 + TB - 1) / TB;
    int nb_edges = (EDGES + TB - 1) / TB;

    // CSR build (shared by all 3 layers) + weight swizzle
    hipLaunchKernelGGL(k_setup, dim3(nb_setup), dim3(TB), 0, stream, packed, W1, wf1, W2, wf2, W3, wf3);
    hipLaunchKernelGGL(k_deg, dim3(nb_edges), dim3(TB), 0, stream, dst, w, packed, rank);
    hipLaunchKernelGGL(k_scan1, dim3(SCAN_NB), dim3(SCAN_TB), 0, stream, packed, dis, repoff, pre, bsum);
    hipLaunchKernelGGL(k_scan2, dim3(1), dim3(256), 0, stream, bsum, boff, rowptr);
    hipLaunchKernelGGL(k_scatter, dim3(nb_edges), dim3(TB), 0, stream, src, dst, w, dis,
                       pre, boff, repoff, rank, rec, rowptr);

    int nb_gemm = (NODES / 16 + 3) / 4;   // 782
    int nb_agg  = (NODES + 3) / 4;        // 12500

    // Layer 1
    hipLaunchKernelGGL((k_gemm<256, 128, true>), dim3(nb_gemm), dim3(TB), 0, stream, (const void*)x, (const uint4*)wf1, h);
    hipLaunchKernelGGL((k_agg<128, true, false>), dim3(nb_agg), dim3(TB), 0, stream, h, rec, rowptr, dis, b1, (void*)xb);

    // Layer 2
    hipLaunchKernelGGL((k_gemm<128, 128, false>), dim3(nb_gemm), dim3(TB), 0, stream, (const void*)xb, (const uint4*)wf2, h);
    hipLaunchKernelGGL((k_agg<128, true, false>), dim3(nb_agg), dim3(TB), 0, stream, h, rec, rowptr, dis, b2, (void*)xb);

    // Layer 3 (no relu, fp32 out)
    hipLaunchKernelGGL((k_gemm<128, 64, false>), dim3(nb_gemm), dim3(TB), 0, stream, (const void*)xb, (const uint4*)wf3, h);
    hipLaunchKernelGGL((k_agg<64, false, true>), dim3(nb_agg), dim3(TB), 0, stream, h, rec, rowptr, dis, b3, d_out);
}

// Round 8
// 300.625 us; speedup vs baseline: 1.0097x; 1.0097x over previous
//
#include <hip/hip_runtime.h>
#include <hip/hip_bf16.h>
#include <stdint.h>

#define NODES 50000
#define EDGES 800000
#define R_REP 8
#define SCAN_TB 256
#define SCAN_NB ((NODES + SCAN_TB - 1) / SCAN_TB)   // 196

typedef short bf16x8 __attribute__((ext_vector_type(8)));
typedef float f32x4 __attribute__((ext_vector_type(4)));

__device__ __forceinline__ unsigned short f2bf(float f) {
    union { float f; unsigned u; } v; v.f = f;
    unsigned r = v.u + 0x7fff + ((v.u >> 16) & 1);   // RNE
    return (unsigned short)(r >> 16);
}
__device__ __forceinline__ float bf2f(unsigned short h) {
    union { float f; unsigned u; } v; v.u = ((unsigned)h) << 16;
    return v.f;
}
__device__ __forceinline__ float bflo(unsigned hv) {
    union { float f; unsigned u; } v; v.u = hv << 16;
    return v.f;
}
__device__ __forceinline__ float bfhi(unsigned hv) {
    union { float f; unsigned u; } v; v.u = hv & 0xffff0000u;
    return v.f;
}

// ---------------- setup: zero replicated counters + W pre-swizzle ----------------
__device__ __forceinline__ void wfrag_one(const float* __restrict__ W, unsigned short* Wf,
                                          int idx, int K, int Nn) {
    int NT = Nn >> 4;
    int lane = idx & 63;
    int f = idx >> 6;
    int nt = f % NT;
    int k0 = (f / NT) << 5;
    int n = (nt << 4) + (lane & 15);
    int kk = k0 + ((lane >> 4) << 3);
    unsigned short o[8];
#pragma unroll
    for (int j = 0; j < 8; j++) o[j] = f2bf(W[(kk + j) * Nn + n]);
    ((uint4*)Wf)[idx] = *(uint4*)o;
}

__global__ void k_setup(unsigned long long* packed,
                        const float* __restrict__ W1, unsigned short* Wf1,
                        const float* __restrict__ W2, unsigned short* Wf2,
                        const float* __restrict__ W3, unsigned short* Wf3) {
    int idx = blockIdx.x * blockDim.x + threadIdx.x;
    if (idx < NODES * R_REP) { packed[idx] = 0ull; return; }
    int k = idx - NODES * R_REP;
    if (k < 4096) wfrag_one(W1, Wf1, k, 256, 128);
    else if (k < 6144) wfrag_one(W2, Wf2, k - 4096, 128, 128);
    else if (k < 7168) wfrag_one(W3, Wf3, k - 6144, 128, 64);
}

// packed[i*R_REP+r]: bits[63:40]=count, bits[39:0]=weighted degree (2^24 fx)
__global__ void k_deg(const int* __restrict__ dst, const float* __restrict__ w,
                      unsigned long long* __restrict__ packed, int* __restrict__ rank) {
    int e = blockIdx.x * blockDim.x + threadIdx.x;
    int r = blockIdx.x & (R_REP - 1);
    if (e < EDGES) {
        int d = dst[e];
        unsigned fx = __float2uint_rn(w[e] * 16777216.0f);   // w * 2^24
        unsigned long long add = (1ull << 40) | (unsigned long long)fx;
        unsigned long long old = atomicAdd(&packed[(size_t)d * R_REP + r], add);
        rank[e] = (int)(old >> 40);
    }
}

__global__ void k_scan1(const unsigned long long* __restrict__ packed,
                        float* __restrict__ dis, int* __restrict__ repoff,
                        int* __restrict__ pre, int* __restrict__ bsum) {
    __shared__ int sm[SCAN_TB];
    int t = threadIdx.x;
    int i = blockIdx.x * SCAN_TB + t;
    int v = 0;
    if (i < NODES) {
        unsigned long long degfx = 0;
        int off = 0;
#pragma unroll
        for (int r = 0; r < R_REP; r++) {
            unsigned long long pk = packed[(size_t)i * R_REP + r];
            repoff[(size_t)r * NODES + i] = off;   // exclusive prefix over replicas
            off += (int)(pk >> 40);
            degfx += (pk & 0xFFFFFFFFFFull);
        }
        v = off;
        float deg = 1.0f + (float)degfx * (1.0f / 16777216.0f);   // +1: self-loop
        dis[i] = rsqrtf(deg);
    }
    sm[t] = v;
    __syncthreads();
    for (int off = 1; off < SCAN_TB; off <<= 1) {
        int x = (t >= off) ? sm[t - off] : 0;
        __syncthreads();
        sm[t] += x;
        __syncthreads();
    }
    if (i < NODES) pre[i] = sm[t] - v;
    if (t == SCAN_TB - 1) bsum[blockIdx.x] = sm[t];
}

__global__ void k_scan2(const int* __restrict__ bsum, int* __restrict__ boff,
                        int* __restrict__ rowptr) {
    __shared__ int sm[256];
    int t = threadIdx.x;
    int v = (t < SCAN_NB) ? bsum[t] : 0;
    sm[t] = v;
    __syncthreads();
    for (int off = 1; off < 256; off <<= 1) {
        int x = (t >= off) ? sm[t - off] : 0;
        __syncthreads();
        sm[t] += x;
        __syncthreads();
    }
    if (t < SCAN_NB) boff[t] = sm[t] - v;
    if (t == 255) rowptr[NODES] = sm[255];
}

__global__ void k_scatter(const int* __restrict__ src, const int* __restrict__ dst,
                          const float* __restrict__ w, const float* __restrict__ dis,
                          const int* __restrict__ pre, const int* __restrict__ boff,
                          const int* __restrict__ repoff, const int* __restrict__ rank,
                          int2* __restrict__ rec, int* __restrict__ rowptr) {
    int e = blockIdx.x * blockDim.x + threadIdx.x;
    int r = blockIdx.x & (R_REP - 1);
    if (e < NODES) rowptr[e] = pre[e] + boff[e >> 8];
    if (e < EDGES) {
        int s = src[e], d = dst[e];
        float nrm = dis[s] * w[e] * dis[d];
        int pos = pre[d] + boff[d >> 8] + repoff[(size_t)r * NODES + d] + rank[e];
        int2 rc; rc.x = s; rc.y = __float_as_int(nrm);
        rec[pos] = rc;
    }
}

// ---------------- GEMM: H[M,N] = A[M,K] @ W[K,N] (bf16 MFMA, fp32 acc) ----------------
template <int K, int Nn, bool A_F32>
__global__ void k_gemm(const void* __restrict__ A_, const uint4* __restrict__ Wf,
                       unsigned short* __restrict__ Hout) {
    constexpr int NT = Nn / 16;
    int lane = threadIdx.x & 63;
    int wave = threadIdx.x >> 6;
    int tile = blockIdx.x * 4 + wave;
    if (tile * 16 >= NODES) return;
    int row = tile * 16 + (lane & 15);
    int kbase = (lane >> 4) * 8;

    f32x4 acc[NT];
#pragma unroll
    for (int i = 0; i < NT; i++) acc[i] = (f32x4){0.f, 0.f, 0.f, 0.f};

    for (int k0 = 0; k0 < K; k0 += 32) {
        bf16x8 a;
        if (A_F32) {
            const float* A = (const float*)A_;
            const float4* p = (const float4*)&A[(size_t)row * K + k0 + kbase];
            float4 u0 = p[0], u1 = p[1];
            unsigned short t[8];
            t[0] = f2bf(u0.x); t[1] = f2bf(u0.y); t[2] = f2bf(u0.z); t[3] = f2bf(u0.w);
            t[4] = f2bf(u1.x); t[5] = f2bf(u1.y); t[6] = f2bf(u1.z); t[7] = f2bf(u1.w);
            a = *(bf16x8*)t;
        } else {
            const unsigned short* A = (const unsigned short*)A_;
            a = *(const bf16x8*)&A[(size_t)row * K + k0 + kbase];
        }
        int fbase = (k0 >> 5) * NT;
#pragma unroll
        for (int nt = 0; nt < NT; nt++) {
            uint4 braw = Wf[(fbase + nt) * 64 + lane];
            bf16x8 b = *(bf16x8*)&braw;
            acc[nt] = __builtin_amdgcn_mfma_f32_16x16x32_bf16(a, b, acc[nt], 0, 0, 0);
        }
    }
    int r0 = (lane >> 4) * 4;
    int col = lane & 15;
#pragma unroll
    for (int nt = 0; nt < NT; nt++) {
#pragma unroll
        for (int r = 0; r < 4; r++) {
            int m = tile * 16 + r0 + r;
            Hout[(size_t)m * Nn + nt * 16 + col] = f2bf(acc[nt][r]);
        }
    }
}

// ---------------- Aggregation: group-per-edge dwordx4 gathers ----------------
// One wave per node. Lanes split into GRP groups of LPG lanes; one gather
// instruction fetches GRP edges' full rows at 16 B/lane (4x fewer memory
// instructions than 4 B/lane, 4 KB in flight per wave). Each lane owns 8
// features; groups accumulate disjoint edge subsets; shfl_xor butterfly
// merges groups; self-term + bias + relu in the epilogue on lanes [0,LPG).
template <int F, bool RELU, bool OUT_F32>
__global__ void k_agg(const unsigned short* __restrict__ H, const int2* __restrict__ rec,
                      const int* __restrict__ rowptr, const float* __restrict__ dis,
                      const float* __restrict__ bias, void* __restrict__ out_) {
    constexpr int LPG = F / 8;        // lanes per group (16 B each -> 8 feats)
    constexpr int GRP = 64 / LPG;     // edges per gather instruction
    int lane = threadIdx.x & 63;
    int node = blockIdx.x * 4 + (threadIdx.x >> 6);
    if (node >= NODES) return;
    node = __builtin_amdgcn_readfirstlane(node);

    int g  = lane / LPG;              // edge-group index
    int fl = lane % LPG;              // feature-lane: features fl*8 .. fl*8+7

    const uint4* Hq = (const uint4*)H;          // row = F/8 uint4s
    constexpr int RQ = F / 8;

    float acc[8];
#pragma unroll
    for (int k = 0; k < 8; k++) acc[k] = 0.f;

    int beg = rowptr[node], end = rowptr[node + 1];
    int last = end - 1;

    for (int c = beg; c < end; c += 4 * GRP) {
        uint4 hv[4]; float nm[4];
#pragma unroll
        for (int d = 0; d < 4; d++) {
            int idx = c + d * GRP + g;
            int cidx = (idx < last) ? idx : last;
            int2 rc = rec[cidx];
            nm[d] = (idx < end) ? __int_as_float(rc.y) : 0.0f;
            hv[d] = Hq[(size_t)rc.x * RQ + fl];
        }
#pragma unroll
        for (int d = 0; d < 4; d++) {
            acc[0] += nm[d] * bflo(hv[d].x); acc[1] += nm[d] * bfhi(hv[d].x);
            acc[2] += nm[d] * bflo(hv[d].y); acc[3] += nm[d] * bfhi(hv[d].y);
            acc[4] += nm[d] * bflo(hv[d].z); acc[5] += nm[d] * bfhi(hv[d].z);
            acc[6] += nm[d] * bflo(hv[d].w); acc[7] += nm[d] * bfhi(hv[d].w);
        }
    }

    // merge groups: butterfly over group bits
#pragma unroll
    for (int off = LPG; off < 64; off <<= 1) {
#pragma unroll
        for (int k = 0; k < 8; k++) acc[k] += __shfl_xor(acc[k], off);
    }

    if (lane < LPG) {
        float sn = dis[node]; sn = sn * sn;    // 1/deg self-loop norm
        uint4 sv = Hq[(size_t)node * RQ + fl];
        acc[0] += sn * bflo(sv.x); acc[1] += sn * bfhi(sv.x);
        acc[2] += sn * bflo(sv.y); acc[3] += sn * bfhi(sv.y);
        acc[4] += sn * bflo(sv.z); acc[5] += sn * bfhi(sv.z);
        acc[6] += sn * bflo(sv.w); acc[7] += sn * bfhi(sv.w);
        float4 bl = ((const float4*)bias)[fl * 2];
        float4 bh = ((const float4*)bias)[fl * 2 + 1];
        acc[0] += bl.x; acc[1] += bl.y; acc[2] += bl.z; acc[3] += bl.w;
        acc[4] += bh.x; acc[5] += bh.y; acc[6] += bh.z; acc[7] += bh.w;
        if (RELU) {
#pragma unroll
            for (int k = 0; k < 8; k++) acc[k] = fmaxf(acc[k], 0.f);
        }
        if (OUT_F32) {
            float4* out = (float4*)out_;
            float4 o0 = {acc[0], acc[1], acc[2], acc[3]};
            float4 o1 = {acc[4], acc[5], acc[6], acc[7]};
            out[(size_t)node * (F / 4) + fl * 2] = o0;
            out[(size_t)node * (F / 4) + fl * 2 + 1] = o1;
        } else {
            unsigned short o[8];
#pragma unroll
            for (int k = 0; k < 8; k++) o[k] = f2bf(acc[k]);
            ((uint4*)out_)[(size_t)node * RQ + fl] = *(uint4*)o;
        }
    }
}

// ---------------- launch ----------------

extern "C" void kernel_launch(void* const* d_in, const int* in_sizes, int n_in,
                              void* d_out, int out_size, void* d_ws, size_t ws_size,
                              hipStream_t stream) {
    const float* x  = (const float*)d_in[0];
    const int*   ei = (const int*)d_in[1];
    const float* w  = (const float*)d_in[2];
    const float* W1 = (const float*)d_in[3];
    const float* b1 = (const float*)d_in[4];
    const float* W2 = (const float*)d_in[5];
    const float* b2 = (const float*)d_in[6];
    const float* W3 = (const float*)d_in[7];
    const float* b3 = (const float*)d_in[8];
    const int* src = ei;
    const int* dst = ei + EDGES;

    char* p = (char*)d_ws;
    auto alloc = [&](size_t n) { char* r = p; p += (n + 511) & ~(size_t)511; return r; };
    unsigned long long* packed = (unsigned long long*)alloc((size_t)NODES * R_REP * 8);
    float*          dis    = (float*)alloc(NODES * 4);
    int*            rowptr = (int*)alloc((NODES + 1) * 4);
    int*            repoff = (int*)alloc((size_t)NODES * R_REP * 4);
    int*            rank   = (int*)alloc(EDGES * 4);
    int*            pre    = (int*)alloc(NODES * 4);
    int*            bsum   = (int*)alloc(SCAN_NB * 4);
    int*            boff   = (int*)alloc(SCAN_NB * 4);
    int2*           rec    = (int2*)alloc(EDGES * 8);
    unsigned short* h      = (unsigned short*)alloc((size_t)NODES * 128 * 2);
    unsigned short* xb     = (unsigned short*)alloc((size_t)NODES * 128 * 2);
    unsigned short* wf1    = (unsigned short*)alloc(256 * 128 * 2);
    unsigned short* wf2    = (unsigned short*)alloc(128 * 128 * 2);
    unsigned short* wf3    = (unsigned short*)alloc(128 * 64 * 2);

    const int TB = 256;
    int nb_setup = (NODES * R_REP + 7168 + TB - 1) / TB;
    int nb_edges = (EDGES + TB - 1) / TB;

    hipLaunchKernelGGL(k_setup, dim3(nb_setup), dim3(TB), 0, stream, packed, W1, wf1, W2, wf2, W3, wf3);
    hipLaunchKernelGGL(k_deg, dim3(nb_edges), dim3(TB), 0, stream, dst, w, packed, rank);
    hipLaunchKernelGGL(k_scan1, dim3(SCAN_NB), dim3(SCAN_TB), 0, stream, packed, dis, repoff, pre, bsum);
    hipLaunchKernelGGL(k_scan2, dim3(1), dim3(256), 0, stream, bsum, boff, rowptr);
    hipLaunchKernelGGL(k_scatter, dim3(nb_edges), dim3(TB), 0, stream, src, dst, w, dis,
                       pre, boff, repoff, rank, rec, rowptr);

    int nb_gemm = (NODES / 16 + 3) / 4;   // 782
    int nb_agg  = (NODES + 3) / 4;        // 12500

    // Layer 1
    hipLaunchKernelGGL((k_gemm<256, 128, true>), dim3(nb_gemm), dim3(TB), 0, stream, (const void*)x, (const uint4*)wf1, h);
    hipLaunchKernelGGL((k_agg<128, true, false>), dim3(nb_agg), dim3(TB), 0, stream, h, rec, rowptr, dis, b1, (void*)xb);

    // Layer 2
    hipLaunchKernelGGL((k_gemm<128, 128, false>), dim3(nb_gemm), dim3(TB), 0, stream, (const void*)xb, (const uint4*)wf2, h);
    hipLaunchKernelGGL((k_agg<128, true, false>), dim3(nb_agg), dim3(TB), 0, stream, h, rec, rowptr, dis, b2, (void*)xb);

    // Layer 3 (no relu, fp32 out)
    hipLaunchKernelGGL((k_gemm<128, 64, false>), dim3(nb_gemm), dim3(TB), 0, stream, (const void*)xb, (const uint4*)wf3, h);
    hipLaunchKernelGGL((k_agg<64, false, true>), dim3(nb_agg), dim3(TB), 0, stream, h, rec, rowptr, dis, b3, d_out);
}

// Round 9
// 292.936 us; speedup vs baseline: 1.0362x; 1.0262x over previous
//
#include <hip/hip_runtime.h>
#include <hip/hip_bf16.h>
#include <stdint.h>

#define NODES 50000
#define EDGES 800000
#define R_REP 8
#define DEG_EPT 4                     // edges per thread in k_deg (atomic MLP)
#define SCAN_TB 256
#define SCAN_NB ((NODES + SCAN_TB - 1) / SCAN_TB)   // 196

typedef short bf16x8 __attribute__((ext_vector_type(8)));
typedef float f32x4 __attribute__((ext_vector_type(4)));

__device__ __forceinline__ unsigned short f2bf(float f) {
    union { float f; unsigned u; } v; v.f = f;
    unsigned r = v.u + 0x7fff + ((v.u >> 16) & 1);   // RNE
    return (unsigned short)(r >> 16);
}
__device__ __forceinline__ float bf2f(unsigned short h) {
    union { float f; unsigned u; } v; v.u = ((unsigned)h) << 16;
    return v.f;
}
__device__ __forceinline__ float bflo(unsigned hv) {
    union { float f; unsigned u; } v; v.u = hv << 16;
    return v.f;
}
__device__ __forceinline__ float bfhi(unsigned hv) {
    union { float f; unsigned u; } v; v.u = hv & 0xffff0000u;
    return v.f;
}

// ---------------- setup: zero replicated counters + W pre-swizzle ----------------
// packed[r*NODES+i] (replica-major: only 2 RMWs per 64B line; node-major at 16
// RMWs/line regressed R7/R8). bits[63:40]=count, bits[39:0]=weighted degree
// (2^24 fixed point). Self-loop weight 1 added at scan time.

__device__ __forceinline__ void wfrag_one(const float* __restrict__ W, unsigned short* Wf,
                                          int idx, int K, int Nn) {
    int NT = Nn >> 4;
    int lane = idx & 63;
    int f = idx >> 6;
    int nt = f % NT;
    int k0 = (f / NT) << 5;
    int n = (nt << 4) + (lane & 15);
    int kk = k0 + ((lane >> 4) << 3);
    unsigned short o[8];
#pragma unroll
    for (int j = 0; j < 8; j++) o[j] = f2bf(W[(kk + j) * Nn + n]);
    ((uint4*)Wf)[idx] = *(uint4*)o;
}

__global__ void k_setup(unsigned long long* packed,
                        const float* __restrict__ W1, unsigned short* Wf1,
                        const float* __restrict__ W2, unsigned short* Wf2,
                        const float* __restrict__ W3, unsigned short* Wf3) {
    int idx = blockIdx.x * blockDim.x + threadIdx.x;
    if (idx < NODES * R_REP) { packed[idx] = 0ull; return; }
    int k = idx - NODES * R_REP;
    if (k < 4096) wfrag_one(W1, Wf1, k, 256, 128);
    else if (k < 6144) wfrag_one(W2, Wf2, k - 4096, 128, 128);
    else if (k < 7168) wfrag_one(W3, Wf3, k - 6144, 128, 64);
}

// k_deg: 4 edges/thread, block covers 1024 contiguous edges (block-strided so
// loads stay coalesced). 4 independent returning atomics issue back-to-back
// before any wait -> 4x atomic MLP per lane. Replica r = blockIdx & 7.
__global__ void k_deg(const int* __restrict__ dst, const float* __restrict__ w,
                      unsigned long long* __restrict__ packed, int* __restrict__ rank) {
    int base = blockIdx.x * (256 * DEG_EPT) + threadIdx.x;
    int r = blockIdx.x & (R_REP - 1);
    unsigned long long olds[DEG_EPT];
#pragma unroll
    for (int q = 0; q < DEG_EPT; q++) {
        int e = base + q * 256;
        if (e < EDGES) {
            int d = dst[e];
            unsigned fx = __float2uint_rn(w[e] * 16777216.0f);   // w * 2^24
            unsigned long long add = (1ull << 40) | (unsigned long long)fx;
            olds[q] = atomicAdd(&packed[(size_t)r * NODES + d], add);
        }
    }
#pragma unroll
    for (int q = 0; q < DEG_EPT; q++) {
        int e = base + q * 256;
        if (e < EDGES) rank[e] = (int)(olds[q] >> 40);
    }
}

// ---- scan1: reduce replicas -> dis + per-replica offsets; block-scan counts ----

__global__ void k_scan1(const unsigned long long* __restrict__ packed,
                        float* __restrict__ dis, int* __restrict__ repoff,
                        int* __restrict__ pre, int* __restrict__ bsum) {
    __shared__ int sm[SCAN_TB];
    int t = threadIdx.x;
    int i = blockIdx.x * SCAN_TB + t;
    int v = 0;
    if (i < NODES) {
        unsigned long long degfx = 0;
        int off = 0;
#pragma unroll
        for (int r = 0; r < R_REP; r++) {
            unsigned long long pk = packed[(size_t)r * NODES + i];
            repoff[(size_t)r * NODES + i] = off;   // exclusive prefix over replicas
            off += (int)(pk >> 40);
            degfx += (pk & 0xFFFFFFFFFFull);
        }
        v = off;
        float deg = 1.0f + (float)degfx * (1.0f / 16777216.0f);   // +1: self-loop
        dis[i] = rsqrtf(deg);
    }
    sm[t] = v;
    __syncthreads();
    for (int off = 1; off < SCAN_TB; off <<= 1) {
        int x = (t >= off) ? sm[t - off] : 0;
        __syncthreads();
        sm[t] += x;
        __syncthreads();
    }
    if (i < NODES) pre[i] = sm[t] - v;
    if (t == SCAN_TB - 1) bsum[blockIdx.x] = sm[t];
}

__global__ void k_scan2(const int* __restrict__ bsum, int* __restrict__ boff,
                        int* __restrict__ rowptr) {
    __shared__ int sm[256];
    int t = threadIdx.x;
    int v = (t < SCAN_NB) ? bsum[t] : 0;
    sm[t] = v;
    __syncthreads();
    for (int off = 1; off < 256; off <<= 1) {
        int x = (t >= off) ? sm[t - off] : 0;
        __syncthreads();
        sm[t] += x;
        __syncthreads();
    }
    if (t < SCAN_NB) boff[t] = sm[t] - v;
    if (t == 255) rowptr[NODES] = sm[255];
}

// atomic-free scatter: pos = (pre[d]+boff[d/256]) + replica offset + rank.
// r must match k_deg's mapping: k_deg block covers 1024 edges -> r=(e>>10)&7.
__global__ void k_scatter(const int* __restrict__ src, const int* __restrict__ dst,
                          const float* __restrict__ w, const float* __restrict__ dis,
                          const int* __restrict__ pre, const int* __restrict__ boff,
                          const int* __restrict__ repoff, const int* __restrict__ rank,
                          int2* __restrict__ rec, int* __restrict__ rowptr) {
    int e = blockIdx.x * blockDim.x + threadIdx.x;
    if (e < NODES) rowptr[e] = pre[e] + boff[e >> 8];
    if (e < EDGES) {
        int r = (e >> 10) & (R_REP - 1);
        int s = src[e], d = dst[e];
        float nrm = dis[s] * w[e] * dis[d];
        int pos = pre[d] + boff[d >> 8] + repoff[(size_t)r * NODES + d] + rank[e];
        int2 rc; rc.x = s; rc.y = __float_as_int(nrm);
        rec[pos] = rc;
    }
}

// ---------------- GEMM: H[M,N] = A[M,K] @ W[K,N] (bf16 MFMA, fp32 acc) ----------------
template <int K, int Nn, bool A_F32>
__global__ void k_gemm(const void* __restrict__ A_, const uint4* __restrict__ Wf,
                       unsigned short* __restrict__ Hout) {
    constexpr int NT = Nn / 16;
    int lane = threadIdx.x & 63;
    int wave = threadIdx.x >> 6;
    int tile = blockIdx.x * 4 + wave;
    if (tile * 16 >= NODES) return;
    int row = tile * 16 + (lane & 15);
    int kbase = (lane >> 4) * 8;

    f32x4 acc[NT];
#pragma unroll
    for (int i = 0; i < NT; i++) acc[i] = (f32x4){0.f, 0.f, 0.f, 0.f};

    for (int k0 = 0; k0 < K; k0 += 32) {
        bf16x8 a;
        if (A_F32) {
            const float* A = (const float*)A_;
            const float4* p = (const float4*)&A[(size_t)row * K + k0 + kbase];
            float4 u0 = p[0], u1 = p[1];
            unsigned short t[8];
            t[0] = f2bf(u0.x); t[1] = f2bf(u0.y); t[2] = f2bf(u0.z); t[3] = f2bf(u0.w);
            t[4] = f2bf(u1.x); t[5] = f2bf(u1.y); t[6] = f2bf(u1.z); t[7] = f2bf(u1.w);
            a = *(bf16x8*)t;
        } else {
            const unsigned short* A = (const unsigned short*)A_;
            a = *(const bf16x8*)&A[(size_t)row * K + k0 + kbase];
        }
        int fbase = (k0 >> 5) * NT;
#pragma unroll
        for (int nt = 0; nt < NT; nt++) {
            uint4 braw = Wf[(fbase + nt) * 64 + lane];
            bf16x8 b = *(bf16x8*)&braw;
            acc[nt] = __builtin_amdgcn_mfma_f32_16x16x32_bf16(a, b, acc[nt], 0, 0, 0);
        }
    }
    int r0 = (lane >> 4) * 4;
    int col = lane & 15;
#pragma unroll
    for (int nt = 0; nt < NT; nt++) {
#pragma unroll
        for (int r = 0; r < 4; r++) {
            int m = tile * 16 + r0 + r;
            Hout[(size_t)m * Nn + nt * 16 + col] = f2bf(acc[nt][r]);
        }
    }
}

// ---------------- Aggregation (best-measured variant, R5/R6: 290 us total) ----
// One wave per node, records on the scalar path (wave-uniform). 8 gathers in
// flight; tail via uniform clamp + zero norm (no divergence, pipe stays full).
template <int F, bool RELU, bool OUT_F32>
__global__ void k_agg(const unsigned short* __restrict__ H, const int2* __restrict__ rec,
                      const int* __restrict__ rowptr, const float* __restrict__ dis,
                      const float* __restrict__ bias, void* __restrict__ out_) {
    constexpr int VPT = F / 64;
    int lane = threadIdx.x & 63;
    int node = blockIdx.x * 4 + (threadIdx.x >> 6);
    if (node >= NODES) return;
    node = __builtin_amdgcn_readfirstlane(node);   // wave-uniform -> SGPR

    const unsigned* H32 = (const unsigned*)H;

    float sn = dis[node]; sn = sn * sn;   // dis^2 = 1/deg (self-loop norm)
    float acc0, acc1 = 0.f;
    if (VPT == 2) {
        unsigned hv = H32[node * 64 + lane];
        acc0 = sn * bflo(hv);
        acc1 = sn * bfhi(hv);
    } else {
        acc0 = sn * bf2f(H[node * 64 + lane]);
    }

    int beg = rowptr[node], end = rowptr[node + 1];
    int last = end - 1;
    for (int j = beg; j < end; j += 8) {
        int ss[8]; float nn[8];
#pragma unroll
        for (int q = 0; q < 8; q++) {
            int idx = j + q;
            idx = (idx < last) ? idx : last;           // uniform clamp
            int2 rc = rec[idx];                        // scalar load, broadcast
            ss[q] = rc.x;
            nn[q] = (j + q < end) ? __int_as_float(rc.y) : 0.0f;
        }
        if (VPT == 2) {
            unsigned hh[8];
#pragma unroll
            for (int q = 0; q < 8; q++) hh[q] = H32[ss[q] * 64 + lane];
#pragma unroll
            for (int q = 0; q < 8; q++) {
                acc0 += nn[q] * bflo(hh[q]);
                acc1 += nn[q] * bfhi(hh[q]);
            }
        } else {
            unsigned short hh[8];
#pragma unroll
            for (int q = 0; q < 8; q++) hh[q] = H[ss[q] * 64 + lane];
#pragma unroll
            for (int q = 0; q < 8; q++) acc0 += nn[q] * bf2f(hh[q]);
        }
    }

    if (OUT_F32) {
        float* out = (float*)out_;
        if (VPT == 2) {
            float x0 = acc0 + bias[lane * 2];
            float x1 = acc1 + bias[lane * 2 + 1];
            if (RELU) { x0 = fmaxf(x0, 0.f); x1 = fmaxf(x1, 0.f); }
            out[(size_t)node * F + lane * 2] = x0;
            out[(size_t)node * F + lane * 2 + 1] = x1;
        } else {
            float x0 = acc0 + bias[lane];
            if (RELU) x0 = fmaxf(x0, 0.f);
            out[(size_t)node * F + lane] = x0;
        }
    } else {
        unsigned short* out = (unsigned short*)out_;
        if (VPT == 2) {
            float x0 = acc0 + bias[lane * 2];
            float x1 = acc1 + bias[lane * 2 + 1];
            if (RELU) { x0 = fmaxf(x0, 0.f); x1 = fmaxf(x1, 0.f); }
            unsigned packed = (unsigned)f2bf(x0) | ((unsigned)f2bf(x1) << 16);
            *(unsigned*)&out[(size_t)node * F + lane * 2] = packed;
        } else {
            float x0 = acc0 + bias[lane];
            if (RELU) x0 = fmaxf(x0, 0.f);
            out[(size_t)node * F + lane] = f2bf(x0);
        }
    }
}

// ---------------- launch ----------------

extern "C" void kernel_launch(void* const* d_in, const int* in_sizes, int n_in,
                              void* d_out, int out_size, void* d_ws, size_t ws_size,
                              hipStream_t stream) {
    const float* x  = (const float*)d_in[0];
    const int*   ei = (const int*)d_in[1];
    const float* w  = (const float*)d_in[2];
    const float* W1 = (const float*)d_in[3];
    const float* b1 = (const float*)d_in[4];
    const float* W2 = (const float*)d_in[5];
    const float* b2 = (const float*)d_in[6];
    const float* W3 = (const float*)d_in[7];
    const float* b3 = (const float*)d_in[8];
    const int* src = ei;
    const int* dst = ei + EDGES;

    char* p = (char*)d_ws;
    auto alloc = [&](size_t n) { char* r = p; p += (n + 511) & ~(size_t)511; return r; };
    unsigned long long* packed = (unsigned long long*)alloc((size_t)NODES * R_REP * 8);
    float*          dis    = (float*)alloc(NODES * 4);
    int*            rowptr = (int*)alloc((NODES + 1) * 4);
    int*            repoff = (int*)alloc((size_t)NODES * R_REP * 4);
    int*            rank   = (int*)alloc(EDGES * 4);
    int*            pre    = (int*)alloc(NODES * 4);
    int*            bsum   = (int*)alloc(SCAN_NB * 4);
    int*            boff   = (int*)alloc(SCAN_NB * 4);
    int2*           rec    = (int2*)alloc(EDGES * 8);
    unsigned short* h      = (unsigned short*)alloc((size_t)NODES * 128 * 2);
    unsigned short* xb     = (unsigned short*)alloc((size_t)NODES * 128 * 2);
    unsigned short* wf1    = (unsigned short*)alloc(256 * 128 * 2);
    unsigned short* wf2    = (unsigned short*)alloc(128 * 128 * 2);
    unsigned short* wf3    = (unsigned short*)alloc(128 * 64 * 2);

    const int TB = 256;
    int nb_setup = (NODES * R_REP + 7168 + TB - 1) / TB;
    int nb_deg   = (EDGES + TB * DEG_EPT - 1) / (TB * DEG_EPT);   // 782
    int nb_edges = (EDGES + TB - 1) / TB;

    hipLaunchKernelGGL(k_setup, dim3(nb_setup), dim3(TB), 0, stream, packed, W1, wf1, W2, wf2, W3, wf3);
    hipLaunchKernelGGL(k_deg, dim3(nb_deg), dim3(TB), 0, stream, dst, w, packed, rank);
    hipLaunchKernelGGL(k_scan1, dim3(SCAN_NB), dim3(SCAN_TB), 0, stream, packed, dis, repoff, pre, bsum);
    hipLaunchKernelGGL(k_scan2, dim3(1), dim3(256), 0, stream, bsum, boff, rowptr);
    hipLaunchKernelGGL(k_scatter, dim3(nb_edges), dim3(TB), 0, stream, src, dst, w, dis,
                       pre, boff, repoff, rank, rec, rowptr);

    int nb_gemm = (NODES / 16 + 3) / 4;   // 782
    int nb_agg  = (NODES + 3) / 4;        // 12500

    // Layer 1
    hipLaunchKernelGGL((k_gemm<256, 128, true>), dim3(nb_gemm), dim3(TB), 0, stream, (const void*)x, (const uint4*)wf1, h);
    hipLaunchKernelGGL((k_agg<128, true, false>), dim3(nb_agg), dim3(TB), 0, stream, h, rec, rowptr, dis, b1, (void*)xb);

    // Layer 2
    hipLaunchKernelGGL((k_gemm<128, 128, false>), dim3(nb_gemm), dim3(TB), 0, stream, (const void*)xb, (const uint4*)wf2, h);
    hipLaunchKernelGGL((k_agg<128, true, false>), dim3(nb_agg), dim3(TB), 0, stream, h, rec, rowptr, dis, b2, (void*)xb);

    // Layer 3 (no relu, fp32 out)
    hipLaunchKernelGGL((k_gemm<128, 64, false>), dim3(nb_gemm), dim3(TB), 0, stream, (const void*)xb, (const uint4*)wf3, h);
    hipLaunchKernelGGL((k_agg<64, false, true>), dim3(nb_agg), dim3(TB), 0, stream, h, rec, rowptr, dis, b3, d_out);
}

// Round 11
// 276.923 us; speedup vs baseline: 1.0961x; 1.0578x over previous
//
#include <hip/hip_runtime.h>
#include <hip/hip_bf16.h>
#include <stdint.h>

#define NODES 50000
#define EDGES 800000
#define R_REP 8
#define DEG_EPT 4
#define SCAN_TB 256
#define SCAN_NB ((NODES + SCAN_TB - 1) / SCAN_TB)   // 196
#define NVB_DEG ((EDGES + 1023) / 1024)             // 782
#define NVB_GEMM ((NODES / 16 + 3) / 4)             // 782

typedef short bf16x8 __attribute__((ext_vector_type(8)));
typedef float f32x4 __attribute__((ext_vector_type(4)));

__device__ __forceinline__ unsigned short f2bf(float f) {
    union { float f; unsigned u; } v; v.f = f;
    unsigned r = v.u + 0x7fff + ((v.u >> 16) & 1);   // RNE
    return (unsigned short)(r >> 16);
}
__device__ __forceinline__ float bf2f(unsigned short h) {
    union { float f; unsigned u; } v; v.u = ((unsigned)h) << 16;
    return v.f;
}
__device__ __forceinline__ float bflo(unsigned hv) {
    union { float f; unsigned u; } v; v.u = hv << 16;
    return v.f;
}
__device__ __forceinline__ float bfhi(unsigned hv) {
    union { float f; unsigned u; } v; v.u = hv & 0xffff0000u;
    return v.f;
}

// ---------------- setup: zero replicated counters + cursor + W pre-swizzle ----
// packed[r*NODES+i] (replica-major). bits[63:40]=count, bits[39:0]=weighted
// degree (2^24 fixed point). Self-loop weight 1 added at scan time.

__device__ __forceinline__ void wfrag_one(const float* __restrict__ W, unsigned short* Wf,
                                          int idx, int K, int Nn) {
    int NT = Nn >> 4;
    int lane = idx & 63;
    int f = idx >> 6;
    int nt = f % NT;
    int k0 = (f / NT) << 5;
    int n = (nt << 4) + (lane & 15);
    int kk = k0 + ((lane >> 4) << 3);
    unsigned short o[8];
#pragma unroll
    for (int j = 0; j < 8; j++) o[j] = f2bf(W[(kk + j) * Nn + n]);
    ((uint4*)Wf)[idx] = *(uint4*)o;
}

__global__ void k_setup(unsigned long long* packed, int* cursor,
                        const float* __restrict__ W1, unsigned short* Wf1,
                        const float* __restrict__ W2, unsigned short* Wf2,
                        const float* __restrict__ W3, unsigned short* Wf3) {
    int idx = blockIdx.x * blockDim.x + threadIdx.x;
    if (idx == 0) *cursor = 0;
    if (idx < NODES * R_REP) { packed[idx] = 0ull; return; }
    int k = idx - NODES * R_REP;
    if (k < 4096) wfrag_one(W1, Wf1, k, 256, 128);
    else if (k < 6144) wfrag_one(W2, Wf2, k - 4096, 128, 128);
    else if (k < 7168) wfrag_one(W3, Wf3, k - 6144, 128, 64);
}

// ---------------- GEMM tile body (shared by fused and standalone kernels) ----
template <int K, int Nn, bool A_F32>
__device__ __forceinline__ void gemm_vb(const void* __restrict__ A_,
                                        const uint4* __restrict__ Wf,
                                        unsigned short* __restrict__ Hout, int vb) {
    constexpr int NT = Nn / 16;
    int lane = threadIdx.x & 63;
    int wave = threadIdx.x >> 6;
    int tile = vb * 4 + wave;
    if (tile * 16 >= NODES) return;
    int row = tile * 16 + (lane & 15);
    int kbase = (lane >> 4) * 8;

    f32x4 acc[NT];
#pragma unroll
    for (int i = 0; i < NT; i++) acc[i] = (f32x4){0.f, 0.f, 0.f, 0.f};

    for (int k0 = 0; k0 < K; k0 += 32) {
        bf16x8 a;
        if (A_F32) {
            const float* A = (const float*)A_;
            const float4* pp = (const float4*)&A[(size_t)row * K + k0 + kbase];
            float4 u0 = pp[0], u1 = pp[1];
            unsigned short t[8];
            t[0] = f2bf(u0.x); t[1] = f2bf(u0.y); t[2] = f2bf(u0.z); t[3] = f2bf(u0.w);
            t[4] = f2bf(u1.x); t[5] = f2bf(u1.y); t[6] = f2bf(u1.z); t[7] = f2bf(u1.w);
            a = *(bf16x8*)t;
        } else {
            const unsigned short* A = (const unsigned short*)A_;
            a = *(const bf16x8*)&A[(size_t)row * K + k0 + kbase];
        }
        int fbase = (k0 >> 5) * NT;
#pragma unroll
        for (int nt = 0; nt < NT; nt++) {
            uint4 braw = Wf[(fbase + nt) * 64 + lane];
            bf16x8 b = *(bf16x8*)&braw;
            acc[nt] = __builtin_amdgcn_mfma_f32_16x16x32_bf16(a, b, acc[nt], 0, 0, 0);
        }
    }
    int r0 = (lane >> 4) * 4;
    int col = lane & 15;
#pragma unroll
    for (int nt = 0; nt < NT; nt++) {
#pragma unroll
        for (int r = 0; r < 4; r++) {
            int m = tile * 16 + r0 + r;
            Hout[(size_t)m * Nn + nt * 16 + col] = f2bf(acc[nt][r]);
        }
    }
}

// ---------------- fused: deg (even blocks) || gemm1 (odd blocks) --------------
// Independent dataflow: deg -> packed/rank; gemm1 -> h. Atomic pipe and MFMA
// pipe overlap on co-resident CUs (m114: separate pipes run concurrently).
__global__ void k_deg_gemm1(const int* __restrict__ dst, const float* __restrict__ w,
                            unsigned long long* __restrict__ packed, int* __restrict__ rank,
                            const float* __restrict__ x, const uint4* __restrict__ Wf1,
                            unsigned short* __restrict__ h) {
    int half = blockIdx.x >> 1;
    if ((blockIdx.x & 1) == 0) {
        if (half >= NVB_DEG) return;
        int base = half * 1024 + threadIdx.x;
        int r = half & (R_REP - 1);
        unsigned long long olds[DEG_EPT];
#pragma unroll
        for (int q = 0; q < DEG_EPT; q++) {
            int e = base + q * 256;
            if (e < EDGES) {
                int d = dst[e];
                unsigned fx = __float2uint_rn(w[e] * 16777216.0f);   // w * 2^24
                unsigned long long add = (1ull << 40) | (unsigned long long)fx;
                olds[q] = atomicAdd(&packed[(size_t)r * NODES + d], add);
            }
        }
#pragma unroll
        for (int q = 0; q < DEG_EPT; q++) {
            int e = base + q * 256;
            if (e < EDGES) rank[e] = (int)(olds[q] >> 40);
        }
    } else {
        if (half >= NVB_GEMM) return;
        gemm_vb<256, 128, true>((const void*)x, Wf1, h, half);
    }
}

// ---- scan: reduce replicas -> dis/repoff; block range claimed by one global
// atomicAdd (segment order across blocks is arbitrary — only per-node
// [start, start+cnt) contiguity matters). Writes rsc[i] = (start, cnt).
__global__ void k_scan(const unsigned long long* __restrict__ packed,
                       float* __restrict__ dis, int* __restrict__ repoff,
                       int2* __restrict__ rsc, int* __restrict__ cursor) {
    __shared__ int sm[SCAN_TB];
    __shared__ int s_base;
    int t = threadIdx.x;
    int i = blockIdx.x * SCAN_TB + t;
    int v = 0;
    if (i < NODES) {
        unsigned long long degfx = 0;
        int off = 0;
#pragma unroll
        for (int r = 0; r < R_REP; r++) {
            unsigned long long pk = packed[(size_t)r * NODES + i];
            repoff[(size_t)r * NODES + i] = off;   // exclusive prefix over replicas
            off += (int)(pk >> 40);
            degfx += (pk & 0xFFFFFFFFFFull);
        }
        v = off;
        dis[i] = rsqrtf(1.0f + (float)degfx * (1.0f / 16777216.0f));  // +1 self-loop
    }
    sm[t] = v;
    __syncthreads();
    for (int off = 1; off < SCAN_TB; off <<= 1) {
        int x2 = (t >= off) ? sm[t - off] : 0;
        __syncthreads();
        sm[t] += x2;
        __syncthreads();
    }
    int incl = sm[t];
    if (t == SCAN_TB - 1) s_base = atomicAdd(cursor, incl);   // claim range
    __syncthreads();
    if (i < NODES) { int2 rs; rs.x = s_base + incl - v; rs.y = v; rsc[i] = rs; }
}

// atomic-free scatter: pos = rsc[d].start + replica offset + rank.
// r must match k_deg's mapping (1024-edge chunks): r = (e>>10)&7.
__global__ void k_scatter(const int* __restrict__ src, const int* __restrict__ dst,
                          const float* __restrict__ w, const float* __restrict__ dis,
                          const int2* __restrict__ rsc, const int* __restrict__ repoff,
                          const int* __restrict__ rank, int2* __restrict__ rec) {
    int e = blockIdx.x * blockDim.x + threadIdx.x;
    if (e < EDGES) {
        int r = (e >> 10) & (R_REP - 1);
        int s = src[e], d = dst[e];
        float nrm = dis[s] * w[e] * dis[d];
        int pos = rsc[d].x + repoff[(size_t)r * NODES + d] + rank[e];
        int2 rc; rc.x = s; rc.y = __float_as_int(nrm);
        rec[pos] = rc;
    }
}

// ---------------- standalone GEMM (layers 2,3) ----------------
template <int K, int Nn, bool A_F32>
__global__ void k_gemm(const void* __restrict__ A_, const uint4* __restrict__ Wf,
                       unsigned short* __restrict__ Hout) {
    gemm_vb<K, Nn, A_F32>(A_, Wf, Hout, blockIdx.x);
}

// ---------------- Aggregation (best-measured R6 variant) ----------------
// One wave per node, records on the scalar path (wave-uniform). 8 gathers in
// flight; tail via uniform clamp + zero norm.
template <int F, bool RELU, bool OUT_F32>
__global__ void k_agg(const unsigned short* __restrict__ H, const int2* __restrict__ rec,
                      const int2* __restrict__ rsc, const float* __restrict__ dis,
                      const float* __restrict__ bias, void* __restrict__ out_) {
    constexpr int VPT = F / 64;
    int lane = threadIdx.x & 63;
    int node = blockIdx.x * 4 + (threadIdx.x >> 6);
    if (node >= NODES) return;
    node = __builtin_amdgcn_readfirstlane(node);   // wave-uniform -> SGPR

    const unsigned* H32 = (const unsigned*)H;

    float sn = dis[node]; sn = sn * sn;   // dis^2 = 1/deg (self-loop norm)
    float acc0, acc1 = 0.f;
    if (VPT == 2) {
        unsigned hv = H32[node * 64 + lane];
        acc0 = sn * bflo(hv);
        acc1 = sn * bfhi(hv);
    } else {
        acc0 = sn * bf2f(H[node * 64 + lane]);
    }

    int2 rs = rsc[node];
    int beg = rs.x, end = rs.x + rs.y;
    int last = end - 1;
    for (int j = beg; j < end; j += 8) {
        int ss[8]; float nn[8];
#pragma unroll
        for (int q = 0; q < 8; q++) {
            int idx = j + q;
            idx = (idx < last) ? idx : last;           // uniform clamp
            int2 rc = rec[idx];                        // scalar load, broadcast
            ss[q] = rc.x;
            nn[q] = (j + q < end) ? __int_as_float(rc.y) : 0.0f;
        }
        if (VPT == 2) {
            unsigned hh[8];
#pragma unroll
            for (int q = 0; q < 8; q++) hh[q] = H32[ss[q] * 64 + lane];
#pragma unroll
            for (int q = 0; q < 8; q++) {
                acc0 += nn[q] * bflo(hh[q]);
                acc1 += nn[q] * bfhi(hh[q]);
            }
        } else {
            unsigned short hh[8];
#pragma unroll
            for (int q = 0; q < 8; q++) hh[q] = H[ss[q] * 64 + lane];
#pragma unroll
            for (int q = 0; q < 8; q++) acc0 += nn[q] * bf2f(hh[q]);
        }
    }

    if (OUT_F32) {
        float* out = (float*)out_;
        if (VPT == 2) {
            float x0 = acc0 + bias[lane * 2];
            float x1 = acc1 + bias[lane * 2 + 1];
            if (RELU) { x0 = fmaxf(x0, 0.f); x1 = fmaxf(x1, 0.f); }
            out[(size_t)node * F + lane * 2] = x0;
            out[(size_t)node * F + lane * 2 + 1] = x1;
        } else {
            float x0 = acc0 + bias[lane];
            if (RELU) x0 = fmaxf(x0, 0.f);
            out[(size_t)node * F + lane] = x0;
        }
    } else {
        unsigned short* out = (unsigned short*)out_;
        if (VPT == 2) {
            float x0 = acc0 + bias[lane * 2];
            float x1 = acc1 + bias[lane * 2 + 1];
            if (RELU) { x0 = fmaxf(x0, 0.f); x1 = fmaxf(x1, 0.f); }
            unsigned pk = (unsigned)f2bf(x0) | ((unsigned)f2bf(x1) << 16);
            *(unsigned*)&out[(size_t)node * F + lane * 2] = pk;
        } else {
            float x0 = acc0 + bias[lane];
            if (RELU) x0 = fmaxf(x0, 0.f);
            out[(size_t)node * F + lane] = f2bf(x0);
        }
    }
}

// ---------------- launch ----------------

extern "C" void kernel_launch(void* const* d_in, const int* in_sizes, int n_in,
                              void* d_out, int out_size, void* d_ws, size_t ws_size,
                              hipStream_t stream) {
    const float* x  = (const float*)d_in[0];
    const int*   ei = (const int*)d_in[1];
    const float* w  = (const float*)d_in[2];
    const float* W1 = (const float*)d_in[3];
    const float* b1 = (const float*)d_in[4];
    const float* W2 = (const float*)d_in[5];
    const float* b2 = (const float*)d_in[6];
    const float* W3 = (const float*)d_in[7];
    const float* b3 = (const float*)d_in[8];
    const int* src = ei;
    const int* dst = ei + EDGES;

    char* p = (char*)d_ws;
    auto alloc = [&](size_t n) { char* r = p; p += (n + 511) & ~(size_t)511; return r; };
    unsigned long long* packed = (unsigned long long*)alloc((size_t)NODES * R_REP * 8);
    float*          dis    = (float*)alloc(NODES * 4);
    int2*           rsc    = (int2*)alloc((size_t)NODES * 8);
    int*            repoff = (int*)alloc((size_t)NODES * R_REP * 4);
    int*            rank   = (int*)alloc(EDGES * 4);
    int*            cursor = (int*)alloc(4);
    int2*           rec    = (int2*)alloc(EDGES * 8);
    unsigned short* h      = (unsigned short*)alloc((size_t)NODES * 128 * 2);
    unsigned short* xb     = (unsigned short*)alloc((size_t)NODES * 128 * 2);
    unsigned short* wf1    = (unsigned short*)alloc(256 * 128 * 2);
    unsigned short* wf2    = (unsigned short*)alloc(128 * 128 * 2);
    unsigned short* wf3    = (unsigned short*)alloc(128 * 64 * 2);

    const int TB = 256;
    int nb_setup = (NODES * R_REP + 7168 + TB - 1) / TB;
    int nb_fused = 2 * ((NVB_DEG > NVB_GEMM) ? NVB_DEG : NVB_GEMM);   // 1564
    int nb_edges = (EDGES + TB - 1) / TB;

    hipLaunchKernelGGL(k_setup, dim3(nb_setup), dim3(TB), 0, stream,
                       packed, cursor, W1, wf1, W2, wf2, W3, wf3);
    hipLaunchKernelGGL(k_deg_gemm1, dim3(nb_fused), dim3(TB), 0, stream,
                       dst, w, packed, rank, x, (const uint4*)wf1, h);
    hipLaunchKernelGGL(k_scan, dim3(SCAN_NB), dim3(SCAN_TB), 0, stream,
                       packed, dis, repoff, rsc, cursor);
    hipLaunchKernelGGL(k_scatter, dim3(nb_edges), dim3(TB), 0, stream,
                       src, dst, w, dis, rsc, repoff, rank, rec);

    int nb_gemm = NVB_GEMM;               // 782
    int nb_agg  = (NODES + 3) / 4;        // 12500

    // Layer 1 aggregation (gemm1 already done in the fused launch)
    hipLaunchKernelGGL((k_agg<128, true, false>), dim3(nb_agg), dim3(TB), 0, stream, h, rec, rsc, dis, b1, (void*)xb);

    // Layer 2
    hipLaunchKernelGGL((k_gemm<128, 128, false>), dim3(nb_gemm), dim3(TB), 0, stream, (const void*)xb, (const uint4*)wf2, h);
    hipLaunchKernelGGL((k_agg<128, true, false>), dim3(nb_agg), dim3(TB), 0, stream, h, rec, rsc, dis, b2, (void*)xb);

    // Layer 3 (no relu, fp32 out)
    hipLaunchKernelGGL((k_gemm<128, 64, false>), dim3(nb_gemm), dim3(TB), 0, stream, (const void*)xb, (const uint4*)wf3, h);
    hipLaunchKernelGGL((k_agg<64, false, true>), dim3(nb_agg), dim3(TB), 0, stream, h, rec, rsc, dis, b3, d_out);
}